// Round 15
// baseline (95.467 us; speedup 1.0000x reference)
//
#include <hip/hip_runtime.h>
#include <math.h>

// NoisyTopkRouter: B=4,S=4096,D=2048,E=64,TOP_K=8
//   convert_w   : W -> per-K-block bf16 hi/lo LDS-image, baked swizzle
//                 unit' = (part*4+u) ^ (col&7)
//   gemm_k1     : 32x128 tile, mfma_f32_32x32x16_bf16 (2x LDS-read efficiency
//                 vs 16x16x32), B via global_load_lds, A reg->bsplit->swizzled
//                 ds_write, dbuf, 40KB LDS -> 2 blocks/CU (barrier decoupling).
//   epi_fast    : one wave/token fast path; near-ties -> flag list   [frozen]
//   refine_dots : one WAVE per (flagged token, expert) fp64 dots     [frozen]
//   refine_final: one wave per flagged token fp64 softmax/top-8      [frozen]

#define KDIM 2048
#define NEXP 64
#define BM 32
#define KB 32
#define NKB (KDIM / KB)       // 64
#define TAU 1.5e-4f

typedef __attribute__((ext_vector_type(8))) short short8v;
typedef __attribute__((ext_vector_type(16))) float f32x16;

__device__ __forceinline__ void bsplit(float v, ushort& h, ushort& l) {
  unsigned u = __float_as_uint(v);
  unsigned hu = (u + 0x8000u) & 0xFFFF0000u;
  h = (ushort)(hu >> 16);
  float r = v - __uint_as_float(hu);
  l = (ushort)((__float_as_uint(r) + 0x8000u) >> 16);
}

// Wpk[blk 0..63][col 0..127][unit' 0..7][8 bf16]; unit' = (p*4+u) ^ (col&7)
__global__ __launch_bounds__(256)
void convert_w(const float* __restrict__ Wr, const float* __restrict__ Wn,
               ushort* __restrict__ Wpk, int* __restrict__ flagcnt) {
  if (blockIdx.x == 0 && threadIdx.x == 0) *flagcnt = 0;
  const int g = blockIdx.x * 256 + threadIdx.x;   // 32768 threads
  const int col = g >> 8;                         // 0..127 (W row / output col)
  const int rem = g & 255;
  const int blk = rem >> 2;                       // 0..63 K-block
  const int u   = rem & 3;                        // k-unit (8 elems)
  const float* srcrow = (col < NEXP) ? (Wr + (size_t)col * KDIM)
                                     : (Wn + (size_t)(col - NEXP) * KDIM);
  const int k = blk * 32 + u * 8;
  const float4 v0 = *(const float4*)(srcrow + k);
  const float4 v1 = *(const float4*)(srcrow + k + 4);
  short8v hv, lv; ushort h, l;
  bsplit(v0.x, h, l); hv[0] = h; lv[0] = l;
  bsplit(v0.y, h, l); hv[1] = h; lv[1] = l;
  bsplit(v0.z, h, l); hv[2] = h; lv[2] = l;
  bsplit(v0.w, h, l); hv[3] = h; lv[3] = l;
  bsplit(v1.x, h, l); hv[4] = h; lv[4] = l;
  bsplit(v1.y, h, l); hv[5] = h; lv[5] = l;
  bsplit(v1.z, h, l); hv[6] = h; lv[6] = l;
  bsplit(v1.w, h, l); hv[7] = h; lv[7] = l;
  const size_t base = (size_t)blk * 8192 + (size_t)col * 64;
  *(short8v*)(Wpk + base + (size_t)((u)     ^ (col & 7)) * 8) = hv;
  *(short8v*)(Wpk + base + (size_t)((4 + u) ^ (col & 7)) * 8) = lv;
}

__global__ __launch_bounds__(256, 2)
void gemm_k1(const float* __restrict__ x, const ushort* __restrict__ Wpk,
             float* __restrict__ scores)
{
  __shared__ ushort Bb[2][8192];   // 2 x 16KB  [col128][unit'8][8]
  __shared__ ushort Ab[2][2048];   // 2 x 4KB   [row32][unit'8][8]

  const int tid  = threadIdx.x;
  const int row0 = blockIdx.x * BM;

  const int wid  = tid >> 6;           // 0..3 -> cols wid*32..wid*32+31
  const int lane = tid & 63;
  const int l31  = lane & 31;
  const int kg   = lane >> 5;          // k-slice 0/1 within a kstep-16

  // A stage map (tid<128): srow = tid>>2 (0..31), su = tid&3 (k-unit)
  const int srow = tid >> 2;
  const int su   = tid & 3;
  const float* xrow = x + (size_t)(row0 + (srow & 31)) * KDIM + su * 8;
  const int fw   = ((srow & 1) << 2) | ((srow >> 1) & 3);
  const int aoff_h = srow * 64 + ((su)     ^ fw) * 8;
  const int aoff_l = srow * 64 + ((4 + su) ^ fw) * 8;

  // fragment read constants
  const int fa   = ((l31 & 1) << 2) | ((l31 >> 1) & 3);   // A swizzle
  const int colB = wid * 32 + l31;
  const int fb   = colB & 7;                              // B swizzle

  f32x16 acc = {0,0,0,0, 0,0,0,0, 0,0,0,0, 0,0,0,0};

  // prologue: stage K-block 0
#pragma unroll
  for (int j = 0; j < 4; ++j) {
    const int idx = j * 256 + tid;
    __builtin_amdgcn_global_load_lds(
        (const __attribute__((address_space(1))) void*)(Wpk + (size_t)idx * 8),
        (__attribute__((address_space(3))) void*)(&Bb[0][(size_t)idx * 8]),
        16, 0, 0);
  }
  if (tid < 128) {
    const float4 xa = *(const float4*)(xrow);
    const float4 xb = *(const float4*)(xrow + 4);
    short8v hv, lv; ushort h, l;
    bsplit(xa.x, h, l); hv[0] = h; lv[0] = l;
    bsplit(xa.y, h, l); hv[1] = h; lv[1] = l;
    bsplit(xa.z, h, l); hv[2] = h; lv[2] = l;
    bsplit(xa.w, h, l); hv[3] = h; lv[3] = l;
    bsplit(xb.x, h, l); hv[4] = h; lv[4] = l;
    bsplit(xb.y, h, l); hv[5] = h; lv[5] = l;
    bsplit(xb.z, h, l); hv[6] = h; lv[6] = l;
    bsplit(xb.w, h, l); hv[7] = h; lv[7] = l;
    *(short8v*)&Ab[0][aoff_h] = hv;
    *(short8v*)&Ab[0][aoff_l] = lv;
  }
  __syncthreads();

  for (int s = 0; s < NKB; ++s) {
    const int cur = s & 1, nxt = cur ^ 1;
    float4 xa, xb;
    if (s + 1 < NKB) {
#pragma unroll
      for (int j = 0; j < 4; ++j) {
        const int idx = j * 256 + tid;
        __builtin_amdgcn_global_load_lds(
            (const __attribute__((address_space(1))) void*)
                (Wpk + (size_t)(s + 1) * 8192 + (size_t)idx * 8),
            (__attribute__((address_space(3))) void*)
                (&Bb[nxt][(size_t)idx * 8]),
            16, 0, 0);
      }
      if (tid < 128) {
        xa = *(const float4*)(xrow + (s + 1) * KB);
        xb = *(const float4*)(xrow + (s + 1) * KB + 4);
      }
    }
    // ---- compute K-block s ----
#pragma unroll
    for (int kk = 0; kk < 2; ++kk) {
      const int u = kk * 2 + kg;
      const short8v ah = *(const short8v*)&Ab[cur][l31 * 64 + ((u)     ^ fa) * 8];
      const short8v al = *(const short8v*)&Ab[cur][l31 * 64 + ((4 + u) ^ fa) * 8];
      const short8v bh = *(const short8v*)&Bb[cur][colB * 64 + ((u)     ^ fb) * 8];
      const short8v bl = *(const short8v*)&Bb[cur][colB * 64 + ((4 + u) ^ fb) * 8];
      acc = __builtin_amdgcn_mfma_f32_32x32x16_bf16(ah, bh, acc, 0, 0, 0);
      acc = __builtin_amdgcn_mfma_f32_32x32x16_bf16(ah, bl, acc, 0, 0, 0);
      acc = __builtin_amdgcn_mfma_f32_32x32x16_bf16(al, bh, acc, 0, 0, 0);
    }
    if (s + 1 < NKB && tid < 128) {
      short8v hv, lv; ushort h, l;
      bsplit(xa.x, h, l); hv[0] = h; lv[0] = l;
      bsplit(xa.y, h, l); hv[1] = h; lv[1] = l;
      bsplit(xa.z, h, l); hv[2] = h; lv[2] = l;
      bsplit(xa.w, h, l); hv[3] = h; lv[3] = l;
      bsplit(xb.x, h, l); hv[4] = h; lv[4] = l;
      bsplit(xb.y, h, l); hv[5] = h; lv[5] = l;
      bsplit(xb.z, h, l); hv[6] = h; lv[6] = l;
      bsplit(xb.w, h, l); hv[7] = h; lv[7] = l;
      *(short8v*)&Ab[nxt][aoff_h] = hv;
      *(short8v*)&Ab[nxt][aoff_l] = lv;
    }
    __syncthreads();
  }

  // C/D layout (32x32): col = lane&31, row = (reg&3) + 8*(reg>>2) + 4*kg
#pragma unroll
  for (int reg = 0; reg < 16; ++reg) {
    const int row = (reg & 3) + 8 * (reg >> 2) + 4 * kg;
    scores[(size_t)(row0 + row) * 128 + colB] = acc[reg];
  }
}

// one wave per token: fast path only; near-ties appended to flag list
__global__ __launch_bounds__(512, 4)
void epi_fast(const float* __restrict__ scores,
              const float* __restrict__ br, const float* __restrict__ bn,
              const float* __restrict__ noise,
              float* __restrict__ out_w, float* __restrict__ out_i,
              float* __restrict__ out_s,
              int* __restrict__ flagcnt, int* __restrict__ flaglist)
{
  const int wid  = threadIdx.x >> 6;
  const int lane = threadIdx.x & 63;
  const int t    = blockIdx.x * 8 + wid;

  const float sr = scores[(size_t)t * 128 + lane];
  const float sn = scores[(size_t)t * 128 + 64 + lane];
  const float z  = sn + bn[lane];
  const float sp = fmaxf(z, 0.f) + log1pf(expf(-fabsf(z)));
  const float v  = sr + br[lane] + noise[(size_t)t * NEXP + lane] * sp;

  float m = v;
#pragma unroll
  for (int d = 32; d; d >>= 1) m = fmaxf(m, __shfl_xor(m, d));
  const float p = expf(v - m);
  float sum = p;
#pragma unroll
  for (int d = 32; d; d >>= 1) sum += __shfl_xor(sum, d);
  out_s[(size_t)t * NEXP + lane] = p / sum;

  float cur = v;
  float vals9[9]; int idx9[9];
#pragma unroll
  for (int it = 0; it < 9; ++it) {
    float mx = cur;
#pragma unroll
    for (int d = 32; d; d >>= 1) mx = fmaxf(mx, __shfl_xor(mx, d));
    const unsigned long long b = __ballot(cur == mx);
    const int li = __ffsll(b) - 1;                 // ties -> lowest index
    vals9[it] = mx; idx9[it] = li;
    if (lane == li) cur = -INFINITY;
  }
  bool flagged = false;
#pragma unroll
  for (int q = 0; q < 8; ++q) flagged |= (vals9[q] - vals9[q + 1] < TAU);

  if (flagged) {
    if (lane == 0) {
      const int s = atomicAdd(flagcnt, 1);
      flaglist[s] = t;
    }
    return;                                        // refine_* writes outputs
  }

  float pt[8]; float ws = 0.f;
#pragma unroll
  for (int q = 0; q < 8; ++q) { pt[q] = expf(vals9[q] - m); ws += pt[q]; }
  if (lane < 8) {
    out_w[(size_t)t * 8 + lane] = pt[lane] / ws;
    out_i[(size_t)t * 8 + lane] = (float)idx9[lane];
  }
}

// one WAVE per (flagged token, expert): nf*64 wave-jobs, grid-strided
__global__ __launch_bounds__(512)
void refine_dots(const float* __restrict__ x,
                 const float* __restrict__ Wr, const float* __restrict__ Wn,
                 const float* __restrict__ br, const float* __restrict__ bn,
                 const float* __restrict__ noise,
                 const int* __restrict__ flagcnt, const int* __restrict__ flaglist,
                 double* __restrict__ nv64)
{
  const int nf    = *flagcnt;
  const int lane  = threadIdx.x & 63;
  const int wslot = (blockIdx.x * 512 + threadIdx.x) >> 6;
  const int nwav  = (gridDim.x * 512) >> 6;
  const int total = nf * 64;

  for (int w = wslot; w < total; w += nwav) {
    const int i = w >> 6, e = w & 63;
    const int t = flaglist[i];
    const float* xr  = x  + (size_t)t * KDIM + lane * 4;
    const float* wrr = Wr + (size_t)e * KDIM + lane * 4;
    const float* wnr = Wn + (size_t)e * KDIM + lane * 4;
    double a0 = 0, a1 = 0, c0 = 0, c1 = 0;
#pragma unroll
    for (int q = 0; q < 8; ++q) {
      const float4 xv = *(const float4*)(xr  + q * 256);
      const float4 wv = *(const float4*)(wrr + q * 256);
      const float4 nv = *(const float4*)(wnr + q * 256);
      a0 = fma((double)xv.x, (double)wv.x, a0);
      a1 = fma((double)xv.y, (double)wv.y, a1);
      a0 = fma((double)xv.z, (double)wv.z, a0);
      a1 = fma((double)xv.w, (double)wv.w, a1);
      c0 = fma((double)xv.x, (double)nv.x, c0);
      c1 = fma((double)xv.y, (double)nv.y, c1);
      c0 = fma((double)xv.z, (double)nv.z, c0);
      c1 = fma((double)xv.w, (double)nv.w, c1);
    }
    double ar = a0 + a1, an = c0 + c1;
#pragma unroll
    for (int d = 32; d; d >>= 1) {
      ar += __shfl_xor(ar, d);
      an += __shfl_xor(an, d);
    }
    if (lane == 0) {
      const double rte = ar + (double)br[e];
      const double zz  = an + (double)bn[e];
      const double spd = fmax(zz, 0.0) + log1p(exp(-fabs(zz)));
      nv64[(size_t)i * 64 + e] = rte + (double)noise[(size_t)t * NEXP + e] * spd;
    }
  }
}

// one wave per flagged token: proven fp64 softmax/top-8 tail
__global__ __launch_bounds__(512)
void refine_final(const double* __restrict__ nv64,
                  const int* __restrict__ flagcnt, const int* __restrict__ flaglist,
                  float* __restrict__ out_w, float* __restrict__ out_i,
                  float* __restrict__ out_s)
{
  const int nf    = *flagcnt;
  const int lane  = threadIdx.x & 63;
  const int wslot = (blockIdx.x * 512 + threadIdx.x) >> 6;
  const int nwav  = (gridDim.x * 512) >> 6;

  for (int i = wslot; i < nf; i += nwav) {
    const int t = flaglist[i];
    const double v64 = nv64[(size_t)i * 64 + lane];
    double md = v64;
#pragma unroll
    for (int d = 32; d; d >>= 1) md = fmax(md, __shfl_xor(md, d));
    const double pe = exp(v64 - md);
    double sd = pe;
#pragma unroll
    for (int d = 32; d; d >>= 1) sd += __shfl_xor(sd, d);
    out_s[(size_t)t * NEXP + lane] = (float)(pe / sd);

    double curd = v64;
    double pv8[8]; int pi8[8]; double wsd = 0.0;
#pragma unroll
    for (int it = 0; it < 8; ++it) {
      double mx = curd;
#pragma unroll
      for (int d = 32; d; d >>= 1) mx = fmax(mx, __shfl_xor(mx, d));
      const unsigned long long b = __ballot(curd == mx);
      const int li = __ffsll(b) - 1;
      pv8[it] = __shfl(pe, li); pi8[it] = li; wsd += pv8[it];
      if (lane == li) curd = -1e300;
    }
    if (lane < 8) {
      out_w[(size_t)t * 8 + lane] = (float)(pv8[lane] / wsd);
      out_i[(size_t)t * 8 + lane] = (float)pi8[lane];
    }
  }
}

extern "C" void kernel_launch(void* const* d_in, const int* in_sizes, int n_in,
                              void* d_out, int out_size, void* d_ws, size_t ws_size,
                              hipStream_t stream) {
  const float* x     = (const float*)d_in[0];
  const float* Wr    = (const float*)d_in[1];
  const float* br    = (const float*)d_in[2];
  const float* Wn    = (const float*)d_in[3];
  const float* bn    = (const float*)d_in[4];
  const float* noise = (const float*)d_in[5];

  const int M = in_sizes[0] / KDIM;                  // 16384 tokens
  float*  scores   = (float*)d_ws;                   // [M][128] f32 = 8 MB
  double* nv64     = (double*)d_ws;                  // aliases scores (dead after
                                                     // epi_fast): [i][64] f64
  ushort* Wpk      = (ushort*)(scores + (size_t)M * 128);  // 1 MB packed W
  int*    flagcnt  = (int*)(Wpk + (size_t)64 * 8192);
  int*    flaglist = flagcnt + 1;                    // up to M ints

  float* out   = (float*)d_out;
  float* out_w = out;                                // [M,8]
  float* out_i = out + (size_t)M * 8;                // [M,8] indices as floats
  float* out_s = out + (size_t)M * 16;               // [M,64]

  convert_w<<<dim3(128), dim3(256), 0, stream>>>(Wr, Wn, Wpk, flagcnt);
  gemm_k1<<<dim3(M / BM), dim3(256), 0, stream>>>(x, Wpk, scores);
  epi_fast<<<dim3(M / 8), dim3(512), 0, stream>>>(scores, br, bn, noise,
                                                  out_w, out_i, out_s,
                                                  flagcnt, flaglist);
  refine_dots<<<dim3(1024), dim3(512), 0, stream>>>(x, Wr, Wn, br, bn, noise,
                                                    flagcnt, flaglist, nv64);
  refine_final<<<dim3(256), dim3(512), 0, stream>>>(nv64, flagcnt, flaglist,
                                                    out_w, out_i, out_s);
}

// Round 16
// 83.767 us; speedup vs baseline: 1.1397x; 1.1397x over previous
//
#include <hip/hip_runtime.h>
#include <math.h>

// NoisyTopkRouter: B=4,S=4096,D=2048,E=64,TOP_K=8
//   convert_w   : W -> per-K-block bf16 hi/lo LDS-image, baked swizzle [frozen]
//   gemm_k1     : 32x128 tile, mfma 32x32x16, SPLIT-K=2: each block does a
//                 K-half -> grid 1024 = 4 blocks/CU (was 2; occ was grid-capped
//                 at 21% with VGPR=52/LDS=40KB allowing 4). Partials summed in
//                 epi_fast.
//   epi_fast    : one wave/token fast path (+2-way partial sum); near-ties ->
//                 flag list
//   refine_dots : one WAVE per (flagged token, expert) fp64 dots     [frozen]
//   refine_final: one wave per flagged token fp64 softmax/top-8      [frozen]

#define KDIM 2048
#define NEXP 64
#define BM 32
#define KB 32
#define KSPLIT 2
#define NKBH (KDIM / KB / KSPLIT)   // 32 K-blocks per half
#define TAU 1.5e-4f

typedef __attribute__((ext_vector_type(8))) short short8v;
typedef __attribute__((ext_vector_type(16))) float f32x16;

__device__ __forceinline__ void bsplit(float v, ushort& h, ushort& l) {
  unsigned u = __float_as_uint(v);
  unsigned hu = (u + 0x8000u) & 0xFFFF0000u;
  h = (ushort)(hu >> 16);
  float r = v - __uint_as_float(hu);
  l = (ushort)((__float_as_uint(r) + 0x8000u) >> 16);
}

// Wpk[blk 0..63][col 0..127][unit' 0..7][8 bf16]; unit' = (p*4+u) ^ (col&7)
__global__ __launch_bounds__(256)
void convert_w(const float* __restrict__ Wr, const float* __restrict__ Wn,
               ushort* __restrict__ Wpk, int* __restrict__ flagcnt) {
  if (blockIdx.x == 0 && threadIdx.x == 0) *flagcnt = 0;
  const int g = blockIdx.x * 256 + threadIdx.x;   // 32768 threads
  const int col = g >> 8;                         // 0..127
  const int rem = g & 255;
  const int blk = rem >> 2;                       // 0..63 K-block
  const int u   = rem & 3;                        // k-unit (8 elems)
  const float* srcrow = (col < NEXP) ? (Wr + (size_t)col * KDIM)
                                     : (Wn + (size_t)(col - NEXP) * KDIM);
  const int k = blk * 32 + u * 8;
  const float4 v0 = *(const float4*)(srcrow + k);
  const float4 v1 = *(const float4*)(srcrow + k + 4);
  short8v hv, lv; ushort h, l;
  bsplit(v0.x, h, l); hv[0] = h; lv[0] = l;
  bsplit(v0.y, h, l); hv[1] = h; lv[1] = l;
  bsplit(v0.z, h, l); hv[2] = h; lv[2] = l;
  bsplit(v0.w, h, l); hv[3] = h; lv[3] = l;
  bsplit(v1.x, h, l); hv[4] = h; lv[4] = l;
  bsplit(v1.y, h, l); hv[5] = h; lv[5] = l;
  bsplit(v1.z, h, l); hv[6] = h; lv[6] = l;
  bsplit(v1.w, h, l); hv[7] = h; lv[7] = l;
  const size_t base = (size_t)blk * 8192 + (size_t)col * 64;
  *(short8v*)(Wpk + base + (size_t)((u)     ^ (col & 7)) * 8) = hv;
  *(short8v*)(Wpk + base + (size_t)((4 + u) ^ (col & 7)) * 8) = lv;
}

__global__ __launch_bounds__(256, 4)
void gemm_k1(const float* __restrict__ x, const ushort* __restrict__ Wpk,
             float* __restrict__ partials)   // [KSPLIT][M][128]
{
  __shared__ ushort Bb[2][8192];   // 2 x 16KB
  __shared__ ushort Ab[2][2048];   // 2 x 4KB

  const int tid  = threadIdx.x;
  const int row0 = blockIdx.x * BM;
  const int ks   = blockIdx.y;                       // K-half 0/1
  const ushort* Wpkh = Wpk + (size_t)ks * NKBH * 8192;
  const int M = gridDim.x * BM;

  const int wid  = tid >> 6;
  const int lane = tid & 63;
  const int l31  = lane & 31;
  const int kg   = lane >> 5;

  const int srow = tid >> 2;
  const int su   = tid & 3;
  const float* xrow = x + (size_t)(row0 + (srow & 31)) * KDIM
                        + (size_t)ks * (KDIM / KSPLIT) + su * 8;
  const int fw   = ((srow & 1) << 2) | ((srow >> 1) & 3);
  const int aoff_h = srow * 64 + ((su)     ^ fw) * 8;
  const int aoff_l = srow * 64 + ((4 + su) ^ fw) * 8;

  const int fa   = ((l31 & 1) << 2) | ((l31 >> 1) & 3);
  const int colB = wid * 32 + l31;
  const int fb   = colB & 7;

  f32x16 acc = {0,0,0,0, 0,0,0,0, 0,0,0,0, 0,0,0,0};

  // prologue: stage K-block 0 of this half
#pragma unroll
  for (int j = 0; j < 4; ++j) {
    const int idx = j * 256 + tid;
    __builtin_amdgcn_global_load_lds(
        (const __attribute__((address_space(1))) void*)(Wpkh + (size_t)idx * 8),
        (__attribute__((address_space(3))) void*)(&Bb[0][(size_t)idx * 8]),
        16, 0, 0);
  }
  if (tid < 128) {
    const float4 xa = *(const float4*)(xrow);
    const float4 xb = *(const float4*)(xrow + 4);
    short8v hv, lv; ushort h, l;
    bsplit(xa.x, h, l); hv[0] = h; lv[0] = l;
    bsplit(xa.y, h, l); hv[1] = h; lv[1] = l;
    bsplit(xa.z, h, l); hv[2] = h; lv[2] = l;
    bsplit(xa.w, h, l); hv[3] = h; lv[3] = l;
    bsplit(xb.x, h, l); hv[4] = h; lv[4] = l;
    bsplit(xb.y, h, l); hv[5] = h; lv[5] = l;
    bsplit(xb.z, h, l); hv[6] = h; lv[6] = l;
    bsplit(xb.w, h, l); hv[7] = h; lv[7] = l;
    *(short8v*)&Ab[0][aoff_h] = hv;
    *(short8v*)&Ab[0][aoff_l] = lv;
  }
  __syncthreads();

  for (int s = 0; s < NKBH; ++s) {
    const int cur = s & 1, nxt = cur ^ 1;
    float4 xa, xb;
    if (s + 1 < NKBH) {
#pragma unroll
      for (int j = 0; j < 4; ++j) {
        const int idx = j * 256 + tid;
        __builtin_amdgcn_global_load_lds(
            (const __attribute__((address_space(1))) void*)
                (Wpkh + (size_t)(s + 1) * 8192 + (size_t)idx * 8),
            (__attribute__((address_space(3))) void*)
                (&Bb[nxt][(size_t)idx * 8]),
            16, 0, 0);
      }
      if (tid < 128) {
        xa = *(const float4*)(xrow + (s + 1) * KB);
        xb = *(const float4*)(xrow + (s + 1) * KB + 4);
      }
    }
#pragma unroll
    for (int kk = 0; kk < 2; ++kk) {
      const int u = kk * 2 + kg;
      const short8v ah = *(const short8v*)&Ab[cur][l31 * 64 + ((u)     ^ fa) * 8];
      const short8v al = *(const short8v*)&Ab[cur][l31 * 64 + ((4 + u) ^ fa) * 8];
      const short8v bh = *(const short8v*)&Bb[cur][colB * 64 + ((u)     ^ fb) * 8];
      const short8v bl = *(const short8v*)&Bb[cur][colB * 64 + ((4 + u) ^ fb) * 8];
      acc = __builtin_amdgcn_mfma_f32_32x32x16_bf16(ah, bh, acc, 0, 0, 0);
      acc = __builtin_amdgcn_mfma_f32_32x32x16_bf16(ah, bl, acc, 0, 0, 0);
      acc = __builtin_amdgcn_mfma_f32_32x32x16_bf16(al, bh, acc, 0, 0, 0);
    }
    if (s + 1 < NKBH && tid < 128) {
      short8v hv, lv; ushort h, l;
      bsplit(xa.x, h, l); hv[0] = h; lv[0] = l;
      bsplit(xa.y, h, l); hv[1] = h; lv[1] = l;
      bsplit(xa.z, h, l); hv[2] = h; lv[2] = l;
      bsplit(xa.w, h, l); hv[3] = h; lv[3] = l;
      bsplit(xb.x, h, l); hv[4] = h; lv[4] = l;
      bsplit(xb.y, h, l); hv[5] = h; lv[5] = l;
      bsplit(xb.z, h, l); hv[6] = h; lv[6] = l;
      bsplit(xb.w, h, l); hv[7] = h; lv[7] = l;
      *(short8v*)&Ab[nxt][aoff_h] = hv;
      *(short8v*)&Ab[nxt][aoff_l] = lv;
    }
    __syncthreads();
  }

  // C/D layout (32x32): col = lane&31, row = (reg&3) + 8*(reg>>2) + 4*kg
  float* dst = partials + (size_t)ks * M * 128;
#pragma unroll
  for (int reg = 0; reg < 16; ++reg) {
    const int row = (reg & 3) + 8 * (reg >> 2) + 4 * kg;
    dst[(size_t)(row0 + row) * 128 + colB] = acc[reg];
  }
}

// one wave per token: fast path; sums the KSPLIT partials inline
__global__ __launch_bounds__(512, 4)
void epi_fast(const float* __restrict__ partials, int M,
              const float* __restrict__ br, const float* __restrict__ bn,
              const float* __restrict__ noise,
              float* __restrict__ out_w, float* __restrict__ out_i,
              float* __restrict__ out_s,
              int* __restrict__ flagcnt, int* __restrict__ flaglist)
{
  const int wid  = threadIdx.x >> 6;
  const int lane = threadIdx.x & 63;
  const int t    = blockIdx.x * 8 + wid;

  const float sr = partials[(size_t)t * 128 + lane]
                 + partials[(size_t)M * 128 + (size_t)t * 128 + lane];
  const float sn = partials[(size_t)t * 128 + 64 + lane]
                 + partials[(size_t)M * 128 + (size_t)t * 128 + 64 + lane];
  const float z  = sn + bn[lane];
  const float sp = fmaxf(z, 0.f) + log1pf(expf(-fabsf(z)));
  const float v  = sr + br[lane] + noise[(size_t)t * NEXP + lane] * sp;

  float m = v;
#pragma unroll
  for (int d = 32; d; d >>= 1) m = fmaxf(m, __shfl_xor(m, d));
  const float p = expf(v - m);
  float sum = p;
#pragma unroll
  for (int d = 32; d; d >>= 1) sum += __shfl_xor(sum, d);
  out_s[(size_t)t * NEXP + lane] = p / sum;

  float cur = v;
  float vals9[9]; int idx9[9];
#pragma unroll
  for (int it = 0; it < 9; ++it) {
    float mx = cur;
#pragma unroll
    for (int d = 32; d; d >>= 1) mx = fmaxf(mx, __shfl_xor(mx, d));
    const unsigned long long b = __ballot(cur == mx);
    const int li = __ffsll(b) - 1;                 // ties -> lowest index
    vals9[it] = mx; idx9[it] = li;
    if (lane == li) cur = -INFINITY;
  }
  bool flagged = false;
#pragma unroll
  for (int q = 0; q < 8; ++q) flagged |= (vals9[q] - vals9[q + 1] < TAU);

  if (flagged) {
    if (lane == 0) {
      const int s = atomicAdd(flagcnt, 1);
      flaglist[s] = t;
    }
    return;                                        // refine_* writes outputs
  }

  float pt[8]; float ws = 0.f;
#pragma unroll
  for (int q = 0; q < 8; ++q) { pt[q] = expf(vals9[q] - m); ws += pt[q]; }
  if (lane < 8) {
    out_w[(size_t)t * 8 + lane] = pt[lane] / ws;
    out_i[(size_t)t * 8 + lane] = (float)idx9[lane];
  }
}

// one WAVE per (flagged token, expert): nf*64 wave-jobs, grid-strided
__global__ __launch_bounds__(512)
void refine_dots(const float* __restrict__ x,
                 const float* __restrict__ Wr, const float* __restrict__ Wn,
                 const float* __restrict__ br, const float* __restrict__ bn,
                 const float* __restrict__ noise,
                 const int* __restrict__ flagcnt, const int* __restrict__ flaglist,
                 double* __restrict__ nv64)
{
  const int nf    = *flagcnt;
  const int lane  = threadIdx.x & 63;
  const int wslot = (blockIdx.x * 512 + threadIdx.x) >> 6;
  const int nwav  = (gridDim.x * 512) >> 6;
  const int total = nf * 64;

  for (int w = wslot; w < total; w += nwav) {
    const int i = w >> 6, e = w & 63;
    const int t = flaglist[i];
    const float* xr  = x  + (size_t)t * KDIM + lane * 4;
    const float* wrr = Wr + (size_t)e * KDIM + lane * 4;
    const float* wnr = Wn + (size_t)e * KDIM + lane * 4;
    double a0 = 0, a1 = 0, c0 = 0, c1 = 0;
#pragma unroll
    for (int q = 0; q < 8; ++q) {
      const float4 xv = *(const float4*)(xr  + q * 256);
      const float4 wv = *(const float4*)(wrr + q * 256);
      const float4 nv = *(const float4*)(wnr + q * 256);
      a0 = fma((double)xv.x, (double)wv.x, a0);
      a1 = fma((double)xv.y, (double)wv.y, a1);
      a0 = fma((double)xv.z, (double)wv.z, a0);
      a1 = fma((double)xv.w, (double)wv.w, a1);
      c0 = fma((double)xv.x, (double)nv.x, c0);
      c1 = fma((double)xv.y, (double)nv.y, c1);
      c0 = fma((double)xv.z, (double)nv.z, c0);
      c1 = fma((double)xv.w, (double)nv.w, c1);
    }
    double ar = a0 + a1, an = c0 + c1;
#pragma unroll
    for (int d = 32; d; d >>= 1) {
      ar += __shfl_xor(ar, d);
      an += __shfl_xor(an, d);
    }
    if (lane == 0) {
      const double rte = ar + (double)br[e];
      const double zz  = an + (double)bn[e];
      const double spd = fmax(zz, 0.0) + log1p(exp(-fabs(zz)));
      nv64[(size_t)i * 64 + e] = rte + (double)noise[(size_t)t * NEXP + e] * spd;
    }
  }
}

// one wave per flagged token: proven fp64 softmax/top-8 tail
__global__ __launch_bounds__(512)
void refine_final(const double* __restrict__ nv64,
                  const int* __restrict__ flagcnt, const int* __restrict__ flaglist,
                  float* __restrict__ out_w, float* __restrict__ out_i,
                  float* __restrict__ out_s)
{
  const int nf    = *flagcnt;
  const int lane  = threadIdx.x & 63;
  const int wslot = (blockIdx.x * 512 + threadIdx.x) >> 6;
  const int nwav  = (gridDim.x * 512) >> 6;

  for (int i = wslot; i < nf; i += nwav) {
    const int t = flaglist[i];
    const double v64 = nv64[(size_t)i * 64 + lane];
    double md = v64;
#pragma unroll
    for (int d = 32; d; d >>= 1) md = fmax(md, __shfl_xor(md, d));
    const double pe = exp(v64 - md);
    double sd = pe;
#pragma unroll
    for (int d = 32; d; d >>= 1) sd += __shfl_xor(sd, d);
    out_s[(size_t)t * NEXP + lane] = (float)(pe / sd);

    double curd = v64;
    double pv8[8]; int pi8[8]; double wsd = 0.0;
#pragma unroll
    for (int it = 0; it < 8; ++it) {
      double mx = curd;
#pragma unroll
      for (int d = 32; d; d >>= 1) mx = fmax(mx, __shfl_xor(mx, d));
      const unsigned long long b = __ballot(curd == mx);
      const int li = __ffsll(b) - 1;
      pv8[it] = __shfl(pe, li); pi8[it] = li; wsd += pv8[it];
      if (lane == li) curd = -1e300;
    }
    if (lane < 8) {
      out_w[(size_t)t * 8 + lane] = (float)(pv8[lane] / wsd);
      out_i[(size_t)t * 8 + lane] = (float)pi8[lane];
    }
  }
}

extern "C" void kernel_launch(void* const* d_in, const int* in_sizes, int n_in,
                              void* d_out, int out_size, void* d_ws, size_t ws_size,
                              hipStream_t stream) {
  const float* x     = (const float*)d_in[0];
  const float* Wr    = (const float*)d_in[1];
  const float* br    = (const float*)d_in[2];
  const float* Wn    = (const float*)d_in[3];
  const float* bn    = (const float*)d_in[4];
  const float* noise = (const float*)d_in[5];

  const int M = in_sizes[0] / KDIM;                  // 16384 tokens
  float*  partials = (float*)d_ws;                   // [2][M][128] f32 = 16 MB
  double* nv64     = (double*)d_ws;                  // aliases partials (dead
                                                     // after epi_fast)
  ushort* Wpk      = (ushort*)(partials + (size_t)KSPLIT * M * 128);  // 1 MB
  int*    flagcnt  = (int*)(Wpk + (size_t)64 * 8192);
  int*    flaglist = flagcnt + 1;                    // up to M ints

  float* out   = (float*)d_out;
  float* out_w = out;                                // [M,8]
  float* out_i = out + (size_t)M * 8;                // [M,8] indices as floats
  float* out_s = out + (size_t)M * 16;               // [M,64]

  convert_w<<<dim3(128), dim3(256), 0, stream>>>(Wr, Wn, Wpk, flagcnt);
  gemm_k1<<<dim3(M / BM, KSPLIT), dim3(256), 0, stream>>>(x, Wpk, partials);
  epi_fast<<<dim3(M / 8), dim3(512), 0, stream>>>(partials, M, br, bn, noise,
                                                  out_w, out_i, out_s,
                                                  flagcnt, flaglist);
  refine_dots<<<dim3(1024), dim3(512), 0, stream>>>(x, Wr, Wn, br, bn, noise,
                                                    flagcnt, flaglist, nv64);
  refine_final<<<dim3(256), dim3(512), 0, stream>>>(nv64, flagcnt, flaglist,
                                                    out_w, out_i, out_s);
}